// Round 4
// baseline (174.189 us; speedup 1.0000x reference)
//
#include <hip/hip_runtime.h>
#include <stdint.h>

#define N_ROWS 100000
#define EPS 1e-6f

typedef float f32x4 __attribute__((ext_vector_type(4)));
typedef __bf16 bf16x8 __attribute__((ext_vector_type(8)));
typedef ushort u16x8 __attribute__((ext_vector_type(8)));

__device__ __forceinline__ ushort f2bf(float f) {
  union { float f; uint32_t u; } v; v.f = f;
  uint32_t u = v.u;
  return (ushort)((u + 0x7FFFu + ((u >> 16) & 1u)) >> 16);
}

// ---- W f32 -> bf16 fragment-linear rearrange ----
// Wf: frag = j16*16 + kt (kt = k/32); lane l holds W[j16*16+(l&15)][kt*32+(l>>4)*8 .. +8]
// offset = (frag*64 + l)*8 ushorts. Wave fragment load = 1KB fully coalesced.
__global__ __launch_bounds__(256) void wconv2_kernel(const float* __restrict__ W,
                                                     ushort* __restrict__ Wf) {
  int t = blockIdx.x * 256 + threadIdx.x;  // 0..32767
  int frag = t >> 6;
  int lane = t & 63;
  int j = (frag >> 4) * 16 + (lane & 15);
  int kb = (frag & 15) * 32 + (lane >> 4) * 8;
  const float* src = W + j * 512 + kb;
  float4 a = *(const float4*)src;
  float4 b = *(const float4*)(src + 4);
  ushort4 lo, hi;
  lo.x = f2bf(a.x); lo.y = f2bf(a.y); lo.z = f2bf(a.z); lo.w = f2bf(a.w);
  hi.x = f2bf(b.x); hi.y = f2bf(b.y); hi.z = f2bf(b.z); hi.w = f2bf(b.w);
  ushort* dst = Wf + (size_t)t * 8;
  *(ushort4*)dst = lo;
  *(ushort4*)(dst + 4) = hi;
}

// ---- fused gather + GEMM + bias + relu + layernorm ----
// 512 threads = 8 waves; tile 64 rows x 512 cols; wave w -> cols [64w, 64w+64).
// Phase 1: gather ALL 4 tables (16 indep 16B loads/thread in flight),
//          cvt->bf16, stage to ONE 64KB swizzled LDS buffer. ONE barrier.
// Phase 2: 16 K-steps, A from LDS, B direct L2->VGPR, no barriers, no HBM.
// Overlap across blocks via 2-blocks/CU co-residency.
__global__ __launch_bounds__(512, 4) void fused4_kernel(
    const float* __restrict__ f1, const float* __restrict__ f2,
    const float* __restrict__ f3, const float* __restrict__ f4,
    const int* __restrict__ i1, const int* __restrict__ i2,
    const int* __restrict__ i3, const int* __restrict__ i4,
    const ushort* __restrict__ Wf, const float* __restrict__ bias,
    const float* __restrict__ gamma, const float* __restrict__ beta,
    float* __restrict__ out) {
  __shared__ ushort Al[64 * 512];  // 64 KB: [row][512 k] bf16, chunk-swizzled
  __shared__ float2 red[64 * 8];   // 4 KB LN cross-wave reduce

  const int t = threadIdx.x;
  const int w = t >> 6;
  const int l = t & 63;
  const int cl = l & 15;
  const int gq = l >> 4;
  const int blk = blockIdx.x;

  // gather: thread covers row (t>>3), 8 floats per (T,h) at h*64 + e8*8
  const int arow = t >> 3;
  const int e8 = t & 7;
  int gi = blk * 64 + arow;
  int gic = gi < N_ROWS ? gi : (N_ROWS - 1);
  const float* tb0 = f1 + (size_t)i1[gic] * 128 + e8 * 8;
  const float* tb1 = f2 + (size_t)i2[gic] * 128 + e8 * 8;
  const float* tb2 = f3 + (size_t)i3[gic] * 128 + e8 * 8;
  const float* tb3 = f4 + (size_t)i4[gic] * 128 + e8 * 8;

  // ---- issue all 16 gather loads (8 floats each) ----
  float4 pa[4][2], pb[4][2];
#pragma unroll
  for (int h = 0; h < 2; ++h) {
    pa[0][h] = *(const float4*)(tb0 + h * 64);
    pb[0][h] = *(const float4*)(tb0 + h * 64 + 4);
    pa[1][h] = *(const float4*)(tb1 + h * 64);
    pb[1][h] = *(const float4*)(tb1 + h * 64 + 4);
    pa[2][h] = *(const float4*)(tb2 + h * 64);
    pb[2][h] = *(const float4*)(tb2 + h * 64 + 4);
    pa[3][h] = *(const float4*)(tb3 + h * 64);
    pb[3][h] = *(const float4*)(tb3 + h * 64 + 4);
  }

  // ---- convert + swizzled 16B LDS writes ----
  // chunk (16B unit within 512-k row) = T*16 + h*8 + e8; swizzle: ^ (row&15)
#pragma unroll
  for (int T = 0; T < 4; ++T)
#pragma unroll
    for (int h = 0; h < 2; ++h) {
      u16x8 o;
      o[0] = f2bf(pa[T][h].x); o[1] = f2bf(pa[T][h].y);
      o[2] = f2bf(pa[T][h].z); o[3] = f2bf(pa[T][h].w);
      o[4] = f2bf(pb[T][h].x); o[5] = f2bf(pb[T][h].y);
      o[6] = f2bf(pb[T][h].z); o[7] = f2bf(pb[T][h].w);
      const int c = (T * 16 + h * 8 + e8) ^ (arow & 15);
      *(u16x8*)(Al + arow * 512 + c * 8) = o;
    }

  // B fragment base: wave w covers j16 = w*4+cb; frag(j16,kt) at ((j16*16+kt)*64+l)*8
  const ushort* Bbase = Wf + ((size_t)w * 4 * 16 * 64 + l) * 8;

  f32x4 acc[4][4];
#pragma unroll
  for (int rb = 0; rb < 4; ++rb)
#pragma unroll
    for (int cb = 0; cb < 4; ++cb)
      acc[rb][cb] = (f32x4){0.f, 0.f, 0.f, 0.f};

  __syncthreads();  // the ONLY pre-epilogue barrier

  // ---- 16 K-steps: pure LDS + L2, no barriers ----
#pragma unroll
  for (int kt = 0; kt < 16; ++kt) {
    bf16x8 bfr[4];
#pragma unroll
    for (int cb = 0; cb < 4; ++cb)
      bfr[cb] = *(const bf16x8*)(Bbase + ((size_t)cb * 16 + kt) * 512);
    bf16x8 af[4];
#pragma unroll
    for (int rb = 0; rb < 4; ++rb) {
      const int c = (kt * 4 + gq) ^ cl;  // swizzled chunk
      af[rb] = *(const bf16x8*)(Al + (rb * 16 + cl) * 512 + c * 8);
    }
#pragma unroll
    for (int cb = 0; cb < 4; ++cb)
#pragma unroll
      for (int rb = 0; rb < 4; ++rb)
        acc[rb][cb] = __builtin_amdgcn_mfma_f32_16x16x32_bf16(
            af[rb], bfr[cb], acc[rb][cb], 0, 0, 0);
  }

  // ---- epilogue: bias + relu + layernorm(512) ----
  const int wcol = w * 64;
  float bia[4], gam[4], bet[4];
#pragma unroll
  for (int cb = 0; cb < 4; ++cb) {
    int col = wcol + cb * 16 + cl;
    bia[cb] = bias[col];
    gam[cb] = gamma[col];
    bet[cb] = beta[col];
  }

#pragma unroll
  for (int rb = 0; rb < 4; ++rb) {
#pragma unroll
    for (int r = 0; r < 4; ++r) {
      float s = 0.f, ss = 0.f;
#pragma unroll
      for (int cb = 0; cb < 4; ++cb) {
        float v = acc[rb][cb][r] + bia[cb];
        v = fmaxf(v, 0.f);
        acc[rb][cb][r] = v;
        s += v;
        ss += v * v;
      }
#pragma unroll
      for (int m = 1; m < 16; m <<= 1) {
        s += __shfl_xor(s, m);
        ss += __shfl_xor(ss, m);
      }
      if (cl == 0) {
        int row = rb * 16 + gq * 4 + r;
        red[row * 8 + w] = make_float2(s, ss);
      }
    }
  }
  __syncthreads();

#pragma unroll
  for (int rb = 0; rb < 4; ++rb) {
#pragma unroll
    for (int r = 0; r < 4; ++r) {
      int row = rb * 16 + gq * 4 + r;
      float S = 0.f, SS = 0.f;
#pragma unroll
      for (int wv = 0; wv < 8; ++wv) {
        float2 p = red[row * 8 + wv];
        S += p.x;
        SS += p.y;
      }
      float mu = S * (1.f / 512.f);
      float var = SS * (1.f / 512.f) - mu * mu;
      float rstd = rsqrtf(var + EPS);
      int g = blk * 64 + row;
      if (g < N_ROWS) {
        float* orow = out + (size_t)g * 512 + wcol;
#pragma unroll
        for (int cb = 0; cb < 4; ++cb)
          orow[cb * 16 + cl] = (acc[rb][cb][r] - mu) * rstd * gam[cb] + bet[cb];
      }
    }
  }
}

extern "C" void kernel_launch(void* const* d_in, const int* in_sizes, int n_in,
                              void* d_out, int out_size, void* d_ws, size_t ws_size,
                              hipStream_t stream) {
  const float* f1 = (const float*)d_in[0];
  const int* i1 = (const int*)d_in[1];
  const float* f2 = (const float*)d_in[2];
  const int* i2 = (const int*)d_in[3];
  const float* f3 = (const float*)d_in[4];
  const int* i3 = (const int*)d_in[5];
  const float* f4 = (const float*)d_in[6];
  const int* i4 = (const int*)d_in[7];
  const float* W = (const float*)d_in[8];
  const float* b = (const float*)d_in[9];
  const float* gm = (const float*)d_in[10];
  const float* bt = (const float*)d_in[11];
  float* out = (float*)d_out;
  ushort* Wf = (ushort*)d_ws;  // 512 KB fragment-linear bf16 W

  wconv2_kernel<<<128, 256, 0, stream>>>(W, Wf);
  fused4_kernel<<<(N_ROWS + 63) / 64, 512, 0, stream>>>(
      f1, f2, f3, f4, i1, i2, i3, i4, Wf, b, gm, bt, out);
}